// Round 1
// baseline (315.420 us; speedup 1.0000x reference)
//
#include <hip/hip_runtime.h>

// SimVQ: x[8,2048,512] f32, codebook[8192,512] f32, W[512,512] f32
// out = concat(quantized[16384*512], indices[16384] (as f32), commit_loss[1])
// Rotation-trick forward value == gathered code exactly, so quantized = codes[idx].
//
// Round 7:
//  - d2_argmin_i8 was LDS-pipe bound (reads 3.15 GB @ wave-tile 32x64 needs 92 TB/s
//    > 69 TB/s ceiling; 1.26e7 bank-conflict cycles from row-stride-64B ds_read_b128).
//    -> wave tile 64x64 (256 thr, 2x2 waves, acc 4x4): reads/op -1.5x (2.1 GB).
//    -> both-sides XOR swizzle (linear LDS dest for global_load_lds, pre-swizzled
//       global source chunk ^ ((t>>3)&3), read addr quad ^ ((l16>>1)&3)): conflict-free.
//  - same swizzle applied to codes_mfma's four 64B-row bf16 tiles (same conflict).

#define DIMK  512
#define CBN   8192
#define MROWS 16384

#define SX 24.0f
#define SC 500.0f
#define INV_SS (1.0f / (SX * SC))
#define DELTA 0.3f
#define DKEY  1231
#define NSLOT 3

// ws layout (bytes)
#define WS_CODES   0UL          // 8192*512*4    = 16,777,216
#define WS_XQ      16777216UL   // 16384*512     =  8,388,608
#define WS_CQ      25165824UL   // 8192*512      =  4,194,304
#define WS_NORMS   29360128UL   // 8192*4
#define WS_CAND    29392896UL   // 16384*128*3*4 = 25,165,824
#define WS_CBH     29392896UL   // alias: cb hi (consumed before cand memset)
#define WS_CBL     37781504UL   // alias: cb lo
#define WS_WH      54558720UL   // 512*512*2 = 524,288
#define WS_WL      55083008UL
#define WS_LOSSP   55607296UL   // 16384*4
// end ~55.7 MB

typedef short s16x8 __attribute__((ext_vector_type(8)));
typedef int   i32x4 __attribute__((ext_vector_type(4)));
typedef float f32x4 __attribute__((ext_vector_type(4)));

__device__ __forceinline__ unsigned short f2bf(float f) {
    unsigned u = __float_as_uint(f);
    unsigned r = u + 0x7FFFu + ((u >> 16) & 1u);   // RTNE
    return (unsigned short)(r >> 16);
}
__device__ __forceinline__ float bf2f(unsigned short h) {
    return __uint_as_float(((unsigned)h) << 16);
}
__device__ __forceinline__ void load_lds16(const void* g, void* l) {
    __builtin_amdgcn_global_load_lds((const __attribute__((address_space(1))) void*)g,
                                     (__attribute__((address_space(3))) void*)l,
                                     16, 0, 0);
}
__device__ __forceinline__ signed char q8(float v, float s) {
    return (signed char)__float2int_rn(fminf(fmaxf(v * s, -127.0f), 127.0f));
}
__device__ __forceinline__ unsigned packSlot(float d, unsigned col) {
    int k = (int)((d + 16.0f) * 4096.0f);
    k = k < 0 ? 0 : (k > 524287 ? 524287 : k);
    return ((unsigned)k << 13) | col;
}

// ---------------- f32 -> bf16 hi + lo ----------------
__global__ __launch_bounds__(256) void split_bf16(const float* __restrict__ in,
                                                  unsigned short* __restrict__ hi,
                                                  unsigned short* __restrict__ lo,
                                                  int n4) {
    int i = blockIdx.x * 256 + threadIdx.x;
    if (i >= n4) return;
    float4 v = ((const float4*)in)[i];
    ushort4 h, l;
    h.x = f2bf(v.x); l.x = f2bf(v.x - bf2f(h.x));
    h.y = f2bf(v.y); l.y = f2bf(v.y - bf2f(h.y));
    h.z = f2bf(v.z); l.z = f2bf(v.z - bf2f(h.z));
    h.w = f2bf(v.w); l.w = f2bf(v.w - bf2f(h.w));
    ((ushort4*)hi)[i] = h;
    ((ushort4*)lo)[i] = l;
}

// ---------------- x -> i8 ----------------
__global__ __launch_bounds__(256) void quant_x(const float* __restrict__ in,
                                               signed char* __restrict__ out, int n4) {
    int i = blockIdx.x * 256 + threadIdx.x;
    if (i >= n4) return;
    float4 v = ((const float4*)in)[i];
    char4 c;
    c.x = q8(v.x, SX); c.y = q8(v.y, SX); c.z = q8(v.z, SX); c.w = q8(v.w, SX);
    ((char4*)out)[i] = c;
}

// ------ codes = cb @ W^T via bf16 hi/lo 3-pass MFMA; emit f32 + i8 + norms ------
// grid (CBN/128, 512/128) = (64,4), 256 threads (4 waves 2x2 of 64x64)
// LDS tiles are [row][32 ushorts = 64B]; chunk = 8 ushorts (16B). Both-sides swizzle:
// source chunk ^ ((t>>3)&3) staged linearly, read at chunk = quad ^ ((l16>>1)&3).
__global__ __launch_bounds__(256) void codes_mfma(
        const unsigned short* __restrict__ Ah_g, const unsigned short* __restrict__ Al_g,
        const unsigned short* __restrict__ Bh_g, const unsigned short* __restrict__ Bl_g,
        float* __restrict__ C, signed char* __restrict__ Cq, float* __restrict__ Norms) {
    __shared__ __align__(16) unsigned short Ahi[128 * 32];
    __shared__ __align__(16) unsigned short Alo[128 * 32];
    __shared__ __align__(16) unsigned short Bhi[128 * 32];
    __shared__ __align__(16) unsigned short Blo[128 * 32];

    const int t    = threadIdx.x;
    const int w    = t >> 6;
    const int lane = t & 63;
    const int quad = lane >> 4;
    const int l16  = lane & 15;
    const int wm   = w & 1, wn = w >> 1;
    const int rowBase = blockIdx.x * 128;
    const int colBase = blockIdx.y * 128;

    f32x4 acc[4][4];
    #pragma unroll
    for (int i = 0; i < 4; ++i)
        #pragma unroll
        for (int j = 0; j < 4; ++j)
            acc[i][j] = (f32x4)(0.0f);

    const int mr = t >> 2;
    const int kq = ((t & 3) ^ ((t >> 3) & 3)) * 8;     // swizzled source chunk (ushorts)
    const size_t gxa = (size_t)(rowBase + mr) * DIMK + kq;
    const size_t gxb = gxa + (size_t)64 * DIMK;
    const size_t gca = (size_t)(colBase + mr) * DIMK + kq;
    const size_t gcb = gca + (size_t)64 * DIMK;
    const int l0 = w * 512;
    const int l1 = 2048 + w * 512;

    const int swz8 = (quad ^ ((l16 >> 1) & 3)) * 8;    // swizzled read chunk (ushorts)

    for (int k0 = 0; k0 < DIMK; k0 += 32) {
        load_lds16(Ah_g + gxa + k0, &Ahi[l0]);
        load_lds16(Ah_g + gxb + k0, &Ahi[l1]);
        load_lds16(Al_g + gxa + k0, &Alo[l0]);
        load_lds16(Al_g + gxb + k0, &Alo[l1]);
        load_lds16(Bh_g + gca + k0, &Bhi[l0]);
        load_lds16(Bh_g + gcb + k0, &Bhi[l1]);
        load_lds16(Bl_g + gca + k0, &Blo[l0]);
        load_lds16(Bl_g + gcb + k0, &Blo[l1]);
        __syncthreads();

        s16x8 ah[4], al[4], bh[4], bl[4];
        #pragma unroll
        for (int i = 0; i < 4; ++i) {
            const int m = wm * 64 + i * 16 + l16;
            ah[i] = *(const s16x8*)&Ahi[m * 32 + swz8];
            al[i] = *(const s16x8*)&Alo[m * 32 + swz8];
        }
        #pragma unroll
        for (int j = 0; j < 4; ++j) {
            const int n = wn * 64 + j * 16 + l16;
            bh[j] = *(const s16x8*)&Bhi[n * 32 + swz8];
            bl[j] = *(const s16x8*)&Blo[n * 32 + swz8];
        }
        #pragma unroll
        for (int i = 0; i < 4; ++i)
            #pragma unroll
            for (int j = 0; j < 4; ++j) {
                acc[i][j] = __builtin_amdgcn_mfma_f32_16x16x32_bf16(ah[i], bh[j], acc[i][j], 0, 0, 0);
                acc[i][j] = __builtin_amdgcn_mfma_f32_16x16x32_bf16(ah[i], bl[j], acc[i][j], 0, 0, 0);
                acc[i][j] = __builtin_amdgcn_mfma_f32_16x16x32_bf16(al[i], bh[j], acc[i][j], 0, 0, 0);
            }
        __syncthreads();
    }

    // epilogue: C/D layout col = j*16+l16, row = i*16+quad*4+r
    #pragma unroll
    for (int i = 0; i < 4; ++i) {
        #pragma unroll
        for (int r = 0; r < 4; ++r) {
            const int row = rowBase + wm * 64 + i * 16 + quad * 4 + r;
            float nsum = 0.0f;
            #pragma unroll
            for (int j = 0; j < 4; ++j) {
                const int col = colBase + wn * 64 + j * 16 + l16;
                const float v = acc[i][j][r];
                C[(size_t)row * DIMK + col] = v;
                Cq[(size_t)row * DIMK + col] = q8(v, SC);
                nsum = fmaf(v, v, nsum);
            }
            nsum += __shfl_xor(nsum, 1, 64);
            nsum += __shfl_xor(nsum, 2, 64);
            nsum += __shfl_xor(nsum, 4, 64);
            nsum += __shfl_xor(nsum, 8, 64);
            if (l16 == 0) atomicAdd(&Norms[row], nsum);
        }
    }
}

// ---------- i8 distance GEMM (MFMA 16x16x64) + ballot candidate emission ----------
// grid: (MROWS/128, CBN/128), 256 threads = 4 waves 2x2, wave tile 64x64 (acc 4x4).
// LDS [128][64B] i8, both-sides swizzle: source chunk ^ ((t>>3)&3) staged linearly
// via global_load_lds, ds_read_b128 at chunk = quad ^ ((l16>>1)&3)  -> conflict-free.
__global__ __launch_bounds__(256, 3) void d2_argmin_i8(
        const signed char* __restrict__ Xq,
        const signed char* __restrict__ Cq,
        const float* __restrict__ Norms,
        unsigned* __restrict__ Cand) {
    __shared__ __align__(16) signed char Ash[128 * 64];
    __shared__ __align__(16) signed char Bsh[128 * 64];

    const int t    = threadIdx.x;
    const int w    = t >> 6;
    const int lane = t & 63;
    const int quad = lane >> 4;
    const int l16  = lane & 15;
    const int wm   = w & 1, wn = w >> 1;
    const int rowBase = blockIdx.x * 128;
    const int colBase = blockIdx.y * 128;

    i32x4 acc[4][4];
    #pragma unroll
    for (int i = 0; i < 4; ++i)
        #pragma unroll
        for (int j = 0; j < 4; ++j)
            acc[i][j] = (i32x4)(0);

    // staging: 256 threads stage A(128x64) and B(128x64) in two insts each
    const int mr  = t >> 2;                              // 0..63
    const int kcs = ((t & 3) ^ ((t >> 3) & 3)) * 16;     // swizzled source chunk (bytes)
    const size_t gxa = (size_t)(rowBase + mr) * DIMK + kcs;
    const size_t gxb = gxa + (size_t)64 * DIMK;
    const size_t gca = (size_t)(colBase + mr) * DIMK + kcs;
    const size_t gcb = gca + (size_t)64 * DIMK;
    const int l0 = w * 1024;            // wave-uniform LDS byte base (rows w*16..+15)
    const int l1 = 4096 + w * 1024;     // rows 64+w*16..+15

    // swizzled read offsets (lane-static; frag i/j at immediate offset i*1024)
    const int swz  = (quad ^ ((l16 >> 1) & 3)) * 16;
    const int aoff = (wm * 64 + l16) * 64 + swz;
    const int boff = (wn * 64 + l16) * 64 + swz;

    for (int k0 = 0; k0 < DIMK; k0 += 64) {
        load_lds16(Xq + gxa + k0, &Ash[l0]);
        load_lds16(Xq + gxb + k0, &Ash[l1]);
        load_lds16(Cq + gca + k0, &Bsh[l0]);
        load_lds16(Cq + gcb + k0, &Bsh[l1]);
        __syncthreads();

        i32x4 af[4];
        #pragma unroll
        for (int i = 0; i < 4; ++i)
            af[i] = *(const i32x4*)&Ash[aoff + i * 1024];
        #pragma unroll
        for (int j = 0; j < 4; ++j) {
            const i32x4 bfj = *(const i32x4*)&Bsh[boff + j * 1024];
            #pragma unroll
            for (int i = 0; i < 4; ++i)
                acc[i][j] = __builtin_amdgcn_mfma_i32_16x16x64_i8(af[i], bfj, acc[i][j], 0, 0, 0);
        }
        __syncthreads();
    }

    // epilogue: d2 = norm - 2*dot*inv; per quad-row min + ballot emission.
    float nrm[4];
    #pragma unroll
    for (int j = 0; j < 4; ++j)
        nrm[j] = Norms[colBase + wn * 64 + j * 16 + l16];

    const int subtile = blockIdx.y * 2 + wn;
    const unsigned long long qmask = 0xFFFFull << (quad * 16);
    const unsigned long long ltm = (lane == 0) ? 0ull : (~0ull >> (64 - lane));
    const unsigned colG = colBase + wn * 64 + l16;

    #pragma unroll
    for (int i = 0; i < 4; ++i) {
        #pragma unroll
        for (int r = 0; r < 4; ++r) {
            float d0 = fmaf((float)acc[i][0][r], -2.0f * INV_SS, nrm[0]);
            float d1 = fmaf((float)acc[i][1][r], -2.0f * INV_SS, nrm[1]);
            float d2v = fmaf((float)acc[i][2][r], -2.0f * INV_SS, nrm[2]);
            float d3 = fmaf((float)acc[i][3][r], -2.0f * INV_SS, nrm[3]);
            float mn = fminf(fminf(d0, d1), fminf(d2v, d3));
            mn = fminf(mn, __shfl_xor(mn, 1, 64));
            mn = fminf(mn, __shfl_xor(mn, 2, 64));
            mn = fminf(mn, __shfl_xor(mn, 4, 64));
            mn = fminf(mn, __shfl_xor(mn, 8, 64));
            const float thr = mn + DELTA;
            unsigned long long b0 = __ballot(d0 <= thr);
            unsigned long long b1 = __ballot(d1 <= thr);
            unsigned long long b2 = __ballot(d2v <= thr);
            unsigned long long b3 = __ballot(d3 <= thr);
            const int row = rowBase + wm * 64 + i * 16 + quad * 4 + r;
            unsigned* slot = Cand + ((size_t)row * 128 + subtile) * NSLOT;
            if (d0 <= thr) {
                int rk = __popcll(b0 & qmask & ltm);
                if (rk < NSLOT) slot[rk] = packSlot(d0, colG + 0);
            }
            if (d1 <= thr) {
                int rk = __popcll(b0 & qmask) + __popcll(b1 & qmask & ltm);
                if (rk < NSLOT) slot[rk] = packSlot(d1, colG + 16);
            }
            if (d2v <= thr) {
                int rk = __popcll(b0 & qmask) + __popcll(b1 & qmask)
                       + __popcll(b2 & qmask & ltm);
                if (rk < NSLOT) slot[rk] = packSlot(d2v, colG + 32);
            }
            if (d3 <= thr) {
                int rk = __popcll(b0 & qmask) + __popcll(b1 & qmask)
                       + __popcll(b2 & qmask) + __popcll(b3 & qmask & ltm);
                if (rk < NSLOT) slot[rk] = packSlot(d3, colG + 48);
            }
        }
    }
}

// ---------- refine candidates exactly (f32) + gather + loss partial ----------
__global__ __launch_bounds__(256) void refine_gather(
        const float* __restrict__ X, const float* __restrict__ Codes,
        const float* __restrict__ Norms, const unsigned* __restrict__ Cand,
        float* __restrict__ outQ, float* __restrict__ outIdx,
        float* __restrict__ lossP) {
    const int t    = threadIdx.x;
    const int w    = t >> 6;
    const int lane = t & 63;
    const int row  = blockIdx.x * 4 + w;

    const unsigned* cp = Cand + (size_t)row * 128 * NSLOT + lane * 6;
    unsigned sl[6];
    #pragma unroll
    for (int s = 0; s < 6; ++s) sl[s] = cp[s];

    unsigned mn = sl[0];
    #pragma unroll
    for (int s = 1; s < 6; ++s) mn = min(mn, sl[s]);
    #pragma unroll
    for (int mask = 1; mask < 64; mask <<= 1)
        mn = min(mn, (unsigned)__shfl((int)mn, lane ^ mask, 64));
    const unsigned thrp = (((mn >> 13) + DKEY) << 13) | 0x1FFFu;

    const float4 xa = *(const float4*)(X + (size_t)row * DIMK + lane * 8);
    const float4 xb = *(const float4*)(X + (size_t)row * DIMK + lane * 8 + 4);

    float bestD = __builtin_inff();
    unsigned bestIdx = 0xFFFFFFFFu;

    #pragma unroll
    for (int s = 0; s < 6; ++s) {
        unsigned long long bm = __ballot(sl[s] <= thrp);
        while (bm) {
            const int src = __ffsll(bm) - 1;
            bm &= bm - 1;
            const unsigned sv = (unsigned)__shfl((int)sl[s], src, 64);
            const unsigned idx = sv & 0x1FFFu;
            const float4 ca = *(const float4*)(Codes + (size_t)idx * DIMK + lane * 8);
            const float4 cbv = *(const float4*)(Codes + (size_t)idx * DIMK + lane * 8 + 4);
            float s2 = xa.x * ca.x + xa.y * ca.y + xa.z * ca.z + xa.w * ca.w
                     + xb.x * cbv.x + xb.y * cbv.y + xb.z * cbv.z + xb.w * cbv.w;
            #pragma unroll
            for (int mm = 1; mm < 64; mm <<= 1) s2 += __shfl_xor(s2, mm, 64);
            const float d2 = fmaf(-2.0f, s2, Norms[idx]);
            if (d2 < bestD || (d2 == bestD && idx < bestIdx)) { bestD = d2; bestIdx = idx; }
        }
    }

    const float4 qa = *(const float4*)(Codes + (size_t)bestIdx * DIMK + lane * 8);
    const float4 qb = *(const float4*)(Codes + (size_t)bestIdx * DIMK + lane * 8 + 4);
    *(float4*)(outQ + (size_t)row * DIMK + lane * 8) = qa;
    *(float4*)(outQ + (size_t)row * DIMK + lane * 8 + 4) = qb;
    float dx0 = xa.x - qa.x, dx1 = xa.y - qa.y, dx2 = xa.z - qa.z, dx3 = xa.w - qa.w;
    float dy0 = xb.x - qb.x, dy1 = xb.y - qb.y, dy2 = xb.z - qb.z, dy3 = xb.w - qb.w;
    float s = dx0 * dx0 + dx1 * dx1 + dx2 * dx2 + dx3 * dx3
            + dy0 * dy0 + dy1 * dy1 + dy2 * dy2 + dy3 * dy3;
    #pragma unroll
    for (int off = 32; off > 0; off >>= 1) s += __shfl_down(s, off);
    if (lane == 0) {
        lossP[row] = s;
        outIdx[row] = (float)bestIdx;
    }
}

__global__ __launch_bounds__(256) void finalize_loss(const float* __restrict__ lossPartials,
                                                     float* __restrict__ outLoss) {
    const int t = threadIdx.x;
    float s = 0.0f;
    for (int i = t; i < MROWS; i += 256) s += lossPartials[i];
    #pragma unroll
    for (int off = 32; off > 0; off >>= 1) s += __shfl_down(s, off);
    __shared__ float red[4];
    if ((t & 63) == 0) red[t >> 6] = s;
    __syncthreads();
    if (t == 0)
        *outLoss = (red[0] + red[1] + red[2] + red[3]) * (1.0f / (float)((size_t)MROWS * DIMK));
}

extern "C" void kernel_launch(void* const* d_in, const int* in_sizes, int n_in,
                              void* d_out, int out_size, void* d_ws, size_t ws_size,
                              hipStream_t stream) {
    const float* x  = (const float*)d_in[0];
    const float* cb = (const float*)d_in[1];
    const float* W  = (const float*)d_in[2];
    float* out = (float*)d_out;

    char* ws = (char*)d_ws;
    float* codes          = (float*)(ws + WS_CODES);
    signed char* xq       = (signed char*)(ws + WS_XQ);
    signed char* cq       = (signed char*)(ws + WS_CQ);
    float* norms          = (float*)(ws + WS_NORMS);
    unsigned* cand        = (unsigned*)(ws + WS_CAND);
    unsigned short* cbh   = (unsigned short*)(ws + WS_CBH);   // aliases cand
    unsigned short* cbl   = (unsigned short*)(ws + WS_CBL);   // aliases cand
    unsigned short* wh    = (unsigned short*)(ws + WS_WH);
    unsigned short* wl    = (unsigned short*)(ws + WS_WL);
    float* lossP          = (float*)(ws + WS_LOSSP);

    hipMemsetAsync(norms, 0, CBN * 4, stream);

    // splits (cbh/cbl live in the cand region; consumed by codes_mfma below)
    split_bf16<<<(CBN * DIMK / 4 + 255) / 256, 256, 0, stream>>>(cb, cbh, cbl, CBN * DIMK / 4);
    split_bf16<<<(DIMK * DIMK / 4 + 255) / 256, 256, 0, stream>>>(W, wh, wl, DIMK * DIMK / 4);
    quant_x<<<(MROWS * DIMK / 4 + 255) / 256, 256, 0, stream>>>(x, xq, MROWS * DIMK / 4);

    // codes = cb @ W^T (3-pass hi/lo MFMA) -> f32 codes + i8 cq + norms
    codes_mfma<<<dim3(CBN / 128, DIMK / 128), 256, 0, stream>>>(cbh, cbl, wh, wl, codes, cq, norms);

    // cand init AFTER codes_mfma (cbh/cbl alias this region)
    hipMemsetAsync(cand, 0xFF, (size_t)MROWS * 128 * NSLOT * 4, stream);

    // i8 MFMA distance + candidate emission (64x64 wave tile, swizzled LDS)
    d2_argmin_i8<<<dim3(MROWS / 128, CBN / 128), 256, 0, stream>>>(xq, cq, norms, cand);

    // exact refine + gather + loss partials
    refine_gather<<<MROWS / 4, 256, 0, stream>>>(x, codes, norms, cand, out,
                                                 out + (size_t)MROWS * DIMK, lossP);
    finalize_loss<<<1, 256, 0, stream>>>(lossP, out + (size_t)MROWS * DIMK + MROWS);
}

// Round 2
// 292.509 us; speedup vs baseline: 1.0783x; 1.0783x over previous
//
#include <hip/hip_runtime.h>

// SimVQ: x[8,2048,512] f32, codebook[8192,512] f32, W[512,512] f32
// out = concat(quantized[16384*512], indices[16384] (as f32), commit_loss[1])
//
// Round 8:
//  R7 post-mortem: swizzle zeroed bank conflicts but 64x64 tile halved occupancy
//  (72 VGPR + 64 AGPR = 136/wave -> 31%); dur 151->158. Real bottleneck: emission
//  epilogue VALU (~40% of cycles) + 37% idle.
//  - d2: back to 512 thr / 8 waves / 32x64 tiles (acc 32 AGPR, ~68 regs -> 75% occ
//    cap), keep swizzle (conflicts stay 0).
//  - emission rewritten branch-free: pack keys straight from i32 dot (1 fma),
//    3-of-4 sorting network + 4-level quad butterfly merge of sorted-3 lists.
//    Keeps 3 SMALLEST keys per (row, 64-col subtile) — superset-quality vs old
//    first-3-within-DELTA; refine unchanged. All slots always written -> the
//    25 MB cand memset kernel is deleted.
//  - prep fused: quant_x + split(cb) + split(W) + norms-zero in one launch.

#define DIMK  512
#define CBN   8192
#define MROWS 16384

#define SX 24.0f
#define SC 500.0f
#define INV_SS (1.0f / (SX * SC))
#define DKEY  1231
#define NSLOT 3

// ws layout (bytes)
#define WS_CODES   0UL          // 8192*512*4    = 16,777,216
#define WS_XQ      16777216UL   // 16384*512     =  8,388,608
#define WS_CQ      25165824UL   // 8192*512      =  4,194,304
#define WS_NORMS   29360128UL   // 8192*4
#define WS_CAND    29392896UL   // 16384*128*3*4 = 25,165,824
#define WS_CBH     29392896UL   // alias: cb hi (consumed before d2 writes cand)
#define WS_CBL     37781504UL   // alias: cb lo
#define WS_WH      54558720UL   // 512*512*2 = 524,288
#define WS_WL      55083008UL
#define WS_LOSSP   55607296UL   // 16384*4
// end ~55.7 MB

typedef short s16x8 __attribute__((ext_vector_type(8)));
typedef int   i32x4 __attribute__((ext_vector_type(4)));
typedef float f32x4 __attribute__((ext_vector_type(4)));

__device__ __forceinline__ unsigned short f2bf(float f) {
    unsigned u = __float_as_uint(f);
    unsigned r = u + 0x7FFFu + ((u >> 16) & 1u);   // RTNE
    return (unsigned short)(r >> 16);
}
__device__ __forceinline__ float bf2f(unsigned short h) {
    return __uint_as_float(((unsigned)h) << 16);
}
__device__ __forceinline__ void load_lds16(const void* g, void* l) {
    __builtin_amdgcn_global_load_lds((const __attribute__((address_space(1))) void*)g,
                                     (__attribute__((address_space(3))) void*)l,
                                     16, 0, 0);
}
__device__ __forceinline__ signed char q8(float v, float s) {
    return (signed char)__float2int_rn(fminf(fmaxf(v * s, -127.0f), 127.0f));
}

// ---------- fused prep: quant_x + split(cb) + split(W) + norms zero ----------
// blocks: [0,8192) x->i8 | [8192,12288) cb->bf16 hi/lo | [12288,12544) W | [12544,12576) norms
__global__ __launch_bounds__(256) void prep(
        const float* __restrict__ x, const float* __restrict__ cb, const float* __restrict__ W,
        signed char* __restrict__ xq,
        unsigned short* __restrict__ cbh, unsigned short* __restrict__ cbl,
        unsigned short* __restrict__ wh, unsigned short* __restrict__ wl,
        float* __restrict__ norms) {
    const int b = blockIdx.x;
    const int t = threadIdx.x;
    if (b < 8192) {
        const int i = b * 256 + t;
        float4 v = ((const float4*)x)[i];
        char4 c;
        c.x = q8(v.x, SX); c.y = q8(v.y, SX); c.z = q8(v.z, SX); c.w = q8(v.w, SX);
        ((char4*)xq)[i] = c;
    } else if (b < 12288) {
        const int i = (b - 8192) * 256 + t;
        float4 v = ((const float4*)cb)[i];
        ushort4 h, l;
        h.x = f2bf(v.x); l.x = f2bf(v.x - bf2f(h.x));
        h.y = f2bf(v.y); l.y = f2bf(v.y - bf2f(h.y));
        h.z = f2bf(v.z); l.z = f2bf(v.z - bf2f(h.z));
        h.w = f2bf(v.w); l.w = f2bf(v.w - bf2f(h.w));
        ((ushort4*)cbh)[i] = h;
        ((ushort4*)cbl)[i] = l;
    } else if (b < 12544) {
        const int i = (b - 12288) * 256 + t;
        float4 v = ((const float4*)W)[i];
        ushort4 h, l;
        h.x = f2bf(v.x); l.x = f2bf(v.x - bf2f(h.x));
        h.y = f2bf(v.y); l.y = f2bf(v.y - bf2f(h.y));
        h.z = f2bf(v.z); l.z = f2bf(v.z - bf2f(h.z));
        h.w = f2bf(v.w); l.w = f2bf(v.w - bf2f(h.w));
        ((ushort4*)wh)[i] = h;
        ((ushort4*)wl)[i] = l;
    } else {
        const int i = (b - 12544) * 256 + t;   // 0..8191
        norms[i] = 0.0f;
    }
}

// ------ codes = cb @ W^T via bf16 hi/lo 3-pass MFMA; emit f32 + i8 + norms ------
// grid (CBN/128, 512/128) = (64,4), 256 threads (4 waves 2x2 of 64x64), swizzled LDS
__global__ __launch_bounds__(256) void codes_mfma(
        const unsigned short* __restrict__ Ah_g, const unsigned short* __restrict__ Al_g,
        const unsigned short* __restrict__ Bh_g, const unsigned short* __restrict__ Bl_g,
        float* __restrict__ C, signed char* __restrict__ Cq, float* __restrict__ Norms) {
    __shared__ __align__(16) unsigned short Ahi[128 * 32];
    __shared__ __align__(16) unsigned short Alo[128 * 32];
    __shared__ __align__(16) unsigned short Bhi[128 * 32];
    __shared__ __align__(16) unsigned short Blo[128 * 32];

    const int t    = threadIdx.x;
    const int w    = t >> 6;
    const int lane = t & 63;
    const int quad = lane >> 4;
    const int l16  = lane & 15;
    const int wm   = w & 1, wn = w >> 1;
    const int rowBase = blockIdx.x * 128;
    const int colBase = blockIdx.y * 128;

    f32x4 acc[4][4];
    #pragma unroll
    for (int i = 0; i < 4; ++i)
        #pragma unroll
        for (int j = 0; j < 4; ++j)
            acc[i][j] = (f32x4)(0.0f);

    const int mr = t >> 2;
    const int kq = ((t & 3) ^ ((t >> 3) & 3)) * 8;     // swizzled source chunk (ushorts)
    const size_t gxa = (size_t)(rowBase + mr) * DIMK + kq;
    const size_t gxb = gxa + (size_t)64 * DIMK;
    const size_t gca = (size_t)(colBase + mr) * DIMK + kq;
    const size_t gcb = gca + (size_t)64 * DIMK;
    const int l0 = w * 512;
    const int l1 = 2048 + w * 512;

    const int swz8 = (quad ^ ((l16 >> 1) & 3)) * 8;    // swizzled read chunk (ushorts)

    for (int k0 = 0; k0 < DIMK; k0 += 32) {
        load_lds16(Ah_g + gxa + k0, &Ahi[l0]);
        load_lds16(Ah_g + gxb + k0, &Ahi[l1]);
        load_lds16(Al_g + gxa + k0, &Alo[l0]);
        load_lds16(Al_g + gxb + k0, &Alo[l1]);
        load_lds16(Bh_g + gca + k0, &Bhi[l0]);
        load_lds16(Bh_g + gcb + k0, &Bhi[l1]);
        load_lds16(Bl_g + gca + k0, &Blo[l0]);
        load_lds16(Bl_g + gcb + k0, &Blo[l1]);
        __syncthreads();

        s16x8 ah[4], al[4], bh[4], bl[4];
        #pragma unroll
        for (int i = 0; i < 4; ++i) {
            const int m = wm * 64 + i * 16 + l16;
            ah[i] = *(const s16x8*)&Ahi[m * 32 + swz8];
            al[i] = *(const s16x8*)&Alo[m * 32 + swz8];
        }
        #pragma unroll
        for (int j = 0; j < 4; ++j) {
            const int n = wn * 64 + j * 16 + l16;
            bh[j] = *(const s16x8*)&Bhi[n * 32 + swz8];
            bl[j] = *(const s16x8*)&Blo[n * 32 + swz8];
        }
        #pragma unroll
        for (int i = 0; i < 4; ++i)
            #pragma unroll
            for (int j = 0; j < 4; ++j) {
                acc[i][j] = __builtin_amdgcn_mfma_f32_16x16x32_bf16(ah[i], bh[j], acc[i][j], 0, 0, 0);
                acc[i][j] = __builtin_amdgcn_mfma_f32_16x16x32_bf16(ah[i], bl[j], acc[i][j], 0, 0, 0);
                acc[i][j] = __builtin_amdgcn_mfma_f32_16x16x32_bf16(al[i], bh[j], acc[i][j], 0, 0, 0);
            }
        __syncthreads();
    }

    // epilogue: C/D layout col = j*16+l16, row = i*16+quad*4+r
    #pragma unroll
    for (int i = 0; i < 4; ++i) {
        #pragma unroll
        for (int r = 0; r < 4; ++r) {
            const int row = rowBase + wm * 64 + i * 16 + quad * 4 + r;
            float nsum = 0.0f;
            #pragma unroll
            for (int j = 0; j < 4; ++j) {
                const int col = colBase + wn * 64 + j * 16 + l16;
                const float v = acc[i][j][r];
                C[(size_t)row * DIMK + col] = v;
                Cq[(size_t)row * DIMK + col] = q8(v, SC);
                nsum = fmaf(v, v, nsum);
            }
            nsum += __shfl_xor(nsum, 1, 64);
            nsum += __shfl_xor(nsum, 2, 64);
            nsum += __shfl_xor(nsum, 4, 64);
            nsum += __shfl_xor(nsum, 8, 64);
            if (l16 == 0) atomicAdd(&Norms[row], nsum);
        }
    }
}

// ---------- i8 distance GEMM (MFMA 16x16x64) + branch-free top-3 emission ----------
// grid: (MROWS/128, CBN/128), 512 threads = 8 waves (4x2), wave tile 32x64 (acc 2x4).
// Swizzled LDS (conflict-free). Emission: pack key = quantized-d<<13 | col directly
// from the i32 dot (1 fma), 3-of-4 sort + 4-level butterfly merge -> 3 smallest
// keys per (row, 64-col subtile), always written (no memset needed).
__global__ __launch_bounds__(512, 6) void d2_argmin_i8(
        const signed char* __restrict__ Xq,
        const signed char* __restrict__ Cq,
        const float* __restrict__ Norms,
        unsigned* __restrict__ Cand) {
    __shared__ __align__(16) signed char Ash[128 * 64];
    __shared__ __align__(16) signed char Bsh[128 * 64];

    const int t    = threadIdx.x;
    const int w    = t >> 6;
    const int lane = t & 63;
    const int quad = lane >> 4;
    const int l16  = lane & 15;
    const int wm   = w & 3, wn = w >> 2;
    const int rowBase = blockIdx.x * 128;
    const int colBase = blockIdx.y * 128;

    i32x4 acc[2][4];
    #pragma unroll
    for (int i = 0; i < 2; ++i)
        #pragma unroll
        for (int j = 0; j < 4; ++j)
            acc[i][j] = (i32x4)(0);

    // staging: 512 threads stage A(128x64) and B(128x64) in one inst each
    const int mr  = t >> 2;                              // 0..127
    const int kcs = ((t & 3) ^ ((t >> 3) & 3)) * 16;     // swizzled source chunk (bytes)
    const size_t gxa = (size_t)(rowBase + mr) * DIMK + kcs;
    const size_t gca = (size_t)(colBase + mr) * DIMK + kcs;
    const int lb = w * 1024;            // wave-uniform LDS byte base

    // swizzled read offsets
    const int swz  = (quad ^ ((l16 >> 1) & 3)) * 16;
    const int aoff = (wm * 32 + l16) * 64 + swz;
    const int boff = (wn * 64 + l16) * 64 + swz;

    // key bias per column group: nq = norm*4096 + 65536 (hoisted; overlaps staging)
    float nq[4];
    #pragma unroll
    for (int j = 0; j < 4; ++j)
        nq[j] = fmaf(Norms[colBase + wn * 64 + j * 16 + l16], 4096.0f, 65536.0f);

    for (int k0 = 0; k0 < DIMK; k0 += 64) {
        load_lds16(Xq + gxa + k0, &Ash[lb]);
        load_lds16(Cq + gca + k0, &Bsh[lb]);
        __syncthreads();

        i32x4 af[2];
        af[0] = *(const i32x4*)&Ash[aoff];
        af[1] = *(const i32x4*)&Ash[aoff + 1024];
        #pragma unroll
        for (int j = 0; j < 4; ++j) {
            const i32x4 bfj = *(const i32x4*)&Bsh[boff + j * 1024];
            acc[0][j] = __builtin_amdgcn_mfma_i32_16x16x64_i8(af[0], bfj, acc[0][j], 0, 0, 0);
            acc[1][j] = __builtin_amdgcn_mfma_i32_16x16x64_i8(af[1], bfj, acc[1][j], 0, 0, 0);
        }
        __syncthreads();
    }

    // ---- branch-free top-3 per (row, 64-col subtile) ----
    // key = clamp((d+16)*4096) << 13 | col, computed as fma(dot, -8192*INV_SS, nq)
    const unsigned colG = colBase + wn * 64 + l16;
    const int subtile = blockIdx.y * 2 + wn;
    const float C2 = -8192.0f * INV_SS;

    #pragma unroll
    for (int i = 0; i < 2; ++i) {
        #pragma unroll
        for (int r = 0; r < 4; ++r) {
            unsigned k[4];
            #pragma unroll
            for (int j = 0; j < 4; ++j) {
                const float kf = fmaf((float)acc[i][j][r], C2, nq[j]);
                int ki = (int)kf;
                ki = ki < 0 ? 0 : ki;
                ki = ki > 524287 ? 524287 : ki;
                k[j] = ((unsigned)ki << 13) | (colG + j * 16);
            }
            // sorted 3-smallest of the lane's 4
            unsigned lo01 = min(k[0], k[1]), hi01 = max(k[0], k[1]);
            unsigned lo23 = min(k[2], k[3]), hi23 = max(k[2], k[3]);
            unsigned a0 = min(lo01, lo23);
            unsigned m  = max(lo01, lo23);
            unsigned tt = min(hi01, hi23);
            unsigned a1 = min(m, tt);
            unsigned a2 = max(m, tt);
            // butterfly merge of sorted-3 lists across the 16-lane quad
            #pragma unroll
            for (int mk = 1; mk < 16; mk <<= 1) {
                const unsigned b0 = __shfl_xor(a0, mk, 64);
                const unsigned b1 = __shfl_xor(a1, mk, 64);
                const unsigned b2 = __shfl_xor(a2, mk, 64);
                const unsigned M0 = max(a0, b0);
                const unsigned m1 = min(a1, b1);
                const unsigned n0 = min(a0, b0);
                a2 = min(max(m1, M0), min(a2, b2));
                a1 = min(M0, m1);
                a0 = n0;
            }
            if (l16 == 0) {
                const int row = rowBase + wm * 32 + i * 16 + quad * 4 + r;
                unsigned* slot = Cand + ((size_t)row * 128 + subtile) * NSLOT;
                slot[0] = a0; slot[1] = a1; slot[2] = a2;
            }
        }
    }
}

// ---------- refine candidates exactly (f32) + gather + loss partial ----------
__global__ __launch_bounds__(256) void refine_gather(
        const float* __restrict__ X, const float* __restrict__ Codes,
        const float* __restrict__ Norms, const unsigned* __restrict__ Cand,
        float* __restrict__ outQ, float* __restrict__ outIdx,
        float* __restrict__ lossP) {
    const int t    = threadIdx.x;
    const int w    = t >> 6;
    const int lane = t & 63;
    const int row  = blockIdx.x * 4 + w;

    const unsigned* cp = Cand + (size_t)row * 128 * NSLOT + lane * 6;
    unsigned sl[6];
    #pragma unroll
    for (int s = 0; s < 6; ++s) sl[s] = cp[s];

    unsigned mn = sl[0];
    #pragma unroll
    for (int s = 1; s < 6; ++s) mn = min(mn, sl[s]);
    #pragma unroll
    for (int mask = 1; mask < 64; mask <<= 1)
        mn = min(mn, (unsigned)__shfl((int)mn, lane ^ mask, 64));
    const unsigned thrp = (((mn >> 13) + DKEY) << 13) | 0x1FFFu;

    const float4 xa = *(const float4*)(X + (size_t)row * DIMK + lane * 8);
    const float4 xb = *(const float4*)(X + (size_t)row * DIMK + lane * 8 + 4);

    float bestD = __builtin_inff();
    unsigned bestIdx = 0xFFFFFFFFu;

    #pragma unroll
    for (int s = 0; s < 6; ++s) {
        unsigned long long bm = __ballot(sl[s] <= thrp);
        while (bm) {
            const int src = __ffsll(bm) - 1;
            bm &= bm - 1;
            const unsigned sv = (unsigned)__shfl((int)sl[s], src, 64);
            const unsigned idx = sv & 0x1FFFu;
            const float4 ca = *(const float4*)(Codes + (size_t)idx * DIMK + lane * 8);
            const float4 cbv = *(const float4*)(Codes + (size_t)idx * DIMK + lane * 8 + 4);
            float s2 = xa.x * ca.x + xa.y * ca.y + xa.z * ca.z + xa.w * ca.w
                     + xb.x * cbv.x + xb.y * cbv.y + xb.z * cbv.z + xb.w * cbv.w;
            #pragma unroll
            for (int mm = 1; mm < 64; mm <<= 1) s2 += __shfl_xor(s2, mm, 64);
            const float d2 = fmaf(-2.0f, s2, Norms[idx]);
            if (d2 < bestD || (d2 == bestD && idx < bestIdx)) { bestD = d2; bestIdx = idx; }
        }
    }

    const float4 qa = *(const float4*)(Codes + (size_t)bestIdx * DIMK + lane * 8);
    const float4 qb = *(const float4*)(Codes + (size_t)bestIdx * DIMK + lane * 8 + 4);
    *(float4*)(outQ + (size_t)row * DIMK + lane * 8) = qa;
    *(float4*)(outQ + (size_t)row * DIMK + lane * 8 + 4) = qb;
    float dx0 = xa.x - qa.x, dx1 = xa.y - qa.y, dx2 = xa.z - qa.z, dx3 = xa.w - qa.w;
    float dy0 = xb.x - qb.x, dy1 = xb.y - qb.y, dy2 = xb.z - qb.z, dy3 = xb.w - qb.w;
    float s = dx0 * dx0 + dx1 * dx1 + dx2 * dx2 + dx3 * dx3
            + dy0 * dy0 + dy1 * dy1 + dy2 * dy2 + dy3 * dy3;
    #pragma unroll
    for (int off = 32; off > 0; off >>= 1) s += __shfl_down(s, off);
    if (lane == 0) {
        lossP[row] = s;
        outIdx[row] = (float)bestIdx;
    }
}

__global__ __launch_bounds__(256) void finalize_loss(const float* __restrict__ lossPartials,
                                                     float* __restrict__ outLoss) {
    const int t = threadIdx.x;
    float s = 0.0f;
    for (int i = t; i < MROWS; i += 256) s += lossPartials[i];
    #pragma unroll
    for (int off = 32; off > 0; off >>= 1) s += __shfl_down(s, off);
    __shared__ float red[4];
    if ((t & 63) == 0) red[t >> 6] = s;
    __syncthreads();
    if (t == 0)
        *outLoss = (red[0] + red[1] + red[2] + red[3]) * (1.0f / (float)((size_t)MROWS * DIMK));
}

extern "C" void kernel_launch(void* const* d_in, const int* in_sizes, int n_in,
                              void* d_out, int out_size, void* d_ws, size_t ws_size,
                              hipStream_t stream) {
    const float* x  = (const float*)d_in[0];
    const float* cb = (const float*)d_in[1];
    const float* W  = (const float*)d_in[2];
    float* out = (float*)d_out;

    char* ws = (char*)d_ws;
    float* codes          = (float*)(ws + WS_CODES);
    signed char* xq       = (signed char*)(ws + WS_XQ);
    signed char* cq       = (signed char*)(ws + WS_CQ);
    float* norms          = (float*)(ws + WS_NORMS);
    unsigned* cand        = (unsigned*)(ws + WS_CAND);
    unsigned short* cbh   = (unsigned short*)(ws + WS_CBH);   // aliases cand
    unsigned short* cbl   = (unsigned short*)(ws + WS_CBL);   // aliases cand
    unsigned short* wh    = (unsigned short*)(ws + WS_WH);
    unsigned short* wl    = (unsigned short*)(ws + WS_WL);
    float* lossP          = (float*)(ws + WS_LOSSP);

    // fused prep: x->i8, cb/W->bf16 hi/lo, norms zero
    prep<<<12576, 256, 0, stream>>>(x, cb, W, xq, cbh, cbl, wh, wl, norms);

    // codes = cb @ W^T (3-pass hi/lo MFMA) -> f32 codes + i8 cq + norms
    codes_mfma<<<dim3(CBN / 128, DIMK / 128), 256, 0, stream>>>(cbh, cbl, wh, wl, codes, cq, norms);

    // i8 MFMA distance + branch-free top-3 emission (writes every slot; no memset)
    d2_argmin_i8<<<dim3(MROWS / 128, CBN / 128), 512, 0, stream>>>(xq, cq, norms, cand);

    // exact refine + gather + loss partials
    refine_gather<<<MROWS / 4, 256, 0, stream>>>(x, codes, norms, cand, out,
                                                 out + (size_t)MROWS * DIMK, lossP);
    finalize_loss<<<1, 256, 0, stream>>>(lossP, out + (size_t)MROWS * DIMK + MROWS);
}